// Round 17
// baseline (152.381 us; speedup 1.0000x reference)
//
#include <hip/hip_runtime.h>
#include <hip/hip_bf16.h>
#include <hip/hip_fp16.h>
#include <math.h>

#define DD 128
#define NEG_SLOPE 0.2f
#define CAP_B 2048          // per-bucket capacity per relation
#define BSHIFT 7            // bucket = dst >> 7 (128 dsts/bucket)
#define MAXNB 512
#define NSCAT 160           // scatter blocks per relation

typedef __attribute__((ext_vector_type(8))) short bf16x8;
typedef __attribute__((ext_vector_type(4))) float f32x4;
typedef __attribute__((ext_vector_type(8))) unsigned short u16x8;

__device__ __forceinline__ short f2bf(float f) {
    __hip_bfloat16 h = __float2bfloat16(f);
    return __builtin_bit_cast(short, h);
}
__device__ __forceinline__ float bf2f(unsigned short u) {
    return __uint_as_float(((unsigned)u) << 16);
}
__device__ __forceinline__ unsigned short f2h(float f) {
    return __builtin_bit_cast(unsigned short, __float2half(f));
}
__device__ __forceinline__ float h2f(unsigned short u) {
    return __half2float(__builtin_bit_cast(__half, u));
}
__device__ __forceinline__ float lrexp(float e) {
    e = (e > 0.f) ? e : NEG_SLOPE * e;
    return __expf(e);
}

// fb column permutation: stored col c' <-> original col (c'&7)*16 + (c'>>3)
__device__ __forceinline__ int permcol(int cp) { return (cp & 7) * 16 + (cp >> 3); }

// ---------------------------------------------------------------------------
// Pack 3 W matrices into bf16 MFMA-B fragment order + init cursors + permuted
// bias sums (pb0 = b_dd+b_dt, pb1 = b_tt+b_dt, both in fb column order).
__global__ __launch_bounds__(256) void pack_init_k(
    const float* __restrict__ W0, const float* __restrict__ W1,
    const float* __restrict__ W2,
    unsigned short* __restrict__ P0, unsigned short* __restrict__ P1,
    unsigned short* __restrict__ P2, int* __restrict__ cursor,
    const float* __restrict__ b_dd, const float* __restrict__ b_tt,
    const float* __restrict__ b_dt, float* __restrict__ pb0,
    float* __restrict__ pb1)
{
    if (blockIdx.x >= 24) {
        const int i = (blockIdx.x - 24) * 256 + threadIdx.x;
        if (i < 4 * MAXNB) cursor[i] = (i & (MAXNB - 1)) * CAP_B;
        if (blockIdx.x == 24) {
            const int t = threadIdx.x;
            if (t < 128) pb0[t] = b_dd[permcol(t)] + b_dt[permcol(t)];
            else         pb1[t - 128] = b_tt[permcol(t - 128)] + b_dt[permcol(t - 128)];
        }
        return;
    }
    const int t = blockIdx.x * 256 + threadIdx.x;
    const int m = t >> 11;
    const int r = t & 2047;
    const float* W = (m == 0) ? W0 : (m == 1) ? W1 : W2;
    unsigned short* P = (m == 0) ? P0 : (m == 1) ? P1 : P2;
    const int lane = r & 63;
    const int tile = r >> 6;
    const int ks = tile >> 3, ct = tile & 7;
    const int col = ct * 16 + (lane & 15);
    const int k0 = ks * 32 + (lane >> 4) * 8;
#pragma unroll
    for (int j = 0; j < 8; ++j)
        P[(size_t)r * 8 + j] = (unsigned short)f2bf(W[(size_t)(k0 + j) * DD + col]);
}

// ---------------------------------------------------------------------------
// Epilogue with permuted vectorized store (fb column order = c').
__device__ __forceinline__ void epi_store(
    f32x4 acc[8], const float* __restrict__ al, const float* __restrict__ ar,
    unsigned short* __restrict__ fb, float* __restrict__ el,
    float* __restrict__ er, int r0, int lane, int nrows)
{
    float pl[4] = {0.f, 0.f, 0.f, 0.f};
    float pr[4] = {0.f, 0.f, 0.f, 0.f};
#pragma unroll
    for (int ct = 0; ct < 8; ++ct) {
        const float alc = al[ct * 16 + (lane & 15)];
        const float arc = ar[ct * 16 + (lane & 15)];
#pragma unroll
        for (int g = 0; g < 4; ++g) {
            pl[g] = fmaf(acc[ct][g], alc, pl[g]);
            pr[g] = fmaf(acc[ct][g], arc, pr[g]);
        }
    }
#pragma unroll
    for (int o = 1; o < 16; o <<= 1) {
#pragma unroll
        for (int g = 0; g < 4; ++g) {
            pl[g] += __shfl_xor(pl[g], o, 16);
            pr[g] += __shfl_xor(pr[g], o, 16);
        }
    }
    if ((lane & 15) == 0) {
#pragma unroll
        for (int g = 0; g < 4; ++g) {
            const int r = r0 + (lane >> 4) * 4 + g;
            if (r < nrows) { el[r] = pl[g]; er[r] = pr[g]; }
        }
    }
#pragma unroll
    for (int g = 0; g < 4; ++g) {
        const int r = r0 + (lane >> 4) * 4 + g;
        if (r < nrows) {
            u16x8 v;
#pragma unroll
            for (int ct = 0; ct < 8; ++ct)
                v[ct] = (unsigned short)f2bf(acc[ct][g]);
            *((u16x8*)(fb + (size_t)r * DD + (lane & 15) * 8)) = v;
        }
    }
}

// ---------------------------------------------------------------------------
// Heterogeneous prep (R12 config): grid.y = 0..3 -> transform variant v
// (W in 32KB LDS, 8 waves x 16 rows); grid.y = 4 -> scatter (NSCAT/relation).
struct Prep5Args {
    const float* x[4];
    const unsigned short* Wp[4];
    const float* al[4]; const float* ar[4];
    unsigned short* fb[4]; float* el[4]; float* er[4];
    const int* src[4]; const int* dst[4];
    int* cursor; unsigned* ebuf;
    int n, nE, nb;
};

__global__ __launch_bounds__(512) void prep5_k(Prep5Args P)
{
    __shared__ unsigned short wlds[2048 * 8];   // 32 KB

    const int v = blockIdx.y;
    if (v < 4) {
        const int lane = threadIdx.x & 63;
        const int wave = threadIdx.x >> 6;          // 0..7
        const int r0 = (blockIdx.x * 8 + wave) * 16;
        if (blockIdx.x * 128 >= P.n) return;

        const uint4* wsrc = (const uint4*)P.Wp[v];
        uint4* wdst = (uint4*)wlds;
#pragma unroll
        for (int i = 0; i < 4; ++i)
            wdst[threadIdx.x + i * 512] = wsrc[threadIdx.x + i * 512];
        __syncthreads();

        if (r0 >= P.n) return;
        const int arow = r0 + (lane & 15);
        const int arow_c = (arow < P.n) ? arow : (P.n - 1);
        const int kbase = (lane >> 4) * 8;
        const float* x = P.x[v];

        f32x4 acc[8];
#pragma unroll
        for (int ct = 0; ct < 8; ++ct) acc[ct] = (f32x4)(0.f);

#pragma unroll
        for (int ks = 0; ks < 4; ++ks) {
            const float* xp = x + (size_t)arow_c * DD + ks * 32 + kbase;
            const float4 a0 = ((const float4*)xp)[0];
            const float4 a1 = ((const float4*)xp)[1];
            bf16x8 af;
            af[0] = f2bf(a0.x); af[1] = f2bf(a0.y); af[2] = f2bf(a0.z); af[3] = f2bf(a0.w);
            af[4] = f2bf(a1.x); af[5] = f2bf(a1.y); af[6] = f2bf(a1.z); af[7] = f2bf(a1.w);
#pragma unroll
            for (int ct = 0; ct < 8; ++ct) {
                const bf16x8 w = *((const bf16x8*)(wlds + ((size_t)(ks * 8 + ct) * 64 + lane) * 8));
                acc[ct] = __builtin_amdgcn_mfma_f32_16x16x32_bf16(af, w, acc[ct], 0, 0, 0);
            }
        }
        epi_store(acc, P.al[v], P.ar[v], P.fb[v], P.el[v], P.er[v], r0, lane, P.n);
        return;
    }

    // ---- bucket scatter (512 threads; aliases wlds for counters) ----
    const int sb = blockIdx.x;
    if (sb >= 4 * NSCAT) return;
    int* cnt_s  = (int*)wlds;
    int* base_s = ((int*)wlds) + MAXNB;
    const int rel = sb / NSCAT;
    const int blk = sb - rel * NSCAT;
    const int* src = P.src[rel];
    const int* dst = P.dst[rel];
    int* cur = P.cursor + (size_t)rel * MAXNB;
    unsigned* eb = P.ebuf + (size_t)rel * P.nb * CAP_B;

    const int t = threadIdx.x;
    const int ch = (P.nE + NSCAT - 1) / NSCAT;
    const int i0 = blk * ch;
    const int i1 = (i0 + ch < P.nE) ? (i0 + ch) : P.nE;

    for (int i = t; i < MAXNB; i += 512) cnt_s[i] = 0;
    __syncthreads();
    for (int i = i0 + t; i < i1; i += 512)
        atomicAdd(&cnt_s[dst[i] >> BSHIFT], 1);
    __syncthreads();
    for (int b = t; b < P.nb; b += 512) {
        const int c = cnt_s[b];
        base_s[b] = c ? atomicAdd(cur + b, c) : 0;
        cnt_s[b] = 0;
    }
    __syncthreads();
    for (int i = i0 + t; i < i1; i += 512) {
        const int dv = dst[i];
        const int b = dv >> BSHIFT;
        const int p = base_s[b] + atomicAdd(&cnt_s[b], 1);
        eb[p] = ((unsigned)(dv & ((1 << BSHIFT) - 1)) << 16) | (unsigned)src[i];
    }
}

// ---------------------------------------------------------------------------
// Fused sort + softmax + aggregate. One block per (bucket, output type).
// Phase 1: counting sort + alpha into LDS (ebuf read twice, no edge buffer).
// Phase 2: 16-lane groups aggregate the bucket's 128 dsts from the LDS list.
struct SortAggArgs {
    const float* elA[2]; const float* erA[2];   // dd, tt
    const float* elB[2]; const float* erB[2];   // td(src=t), dt(src=d)
    const unsigned short* fbA[2];               // dd, tt
    const unsigned short* fbB[2];               // td: fb_dt_t, dt: fb_dt_d
    const float* pb[2];
    float* out[2];
    int n, nb;
};

__device__ __forceinline__ void fma8v(
    float a, const u16x8& v, float4& o0, float4& o1)
{
    o0.x = fmaf(a, bf2f(v[0]), o0.x);
    o0.y = fmaf(a, bf2f(v[1]), o0.y);
    o0.z = fmaf(a, bf2f(v[2]), o0.z);
    o0.w = fmaf(a, bf2f(v[3]), o0.w);
    o1.x = fmaf(a, bf2f(v[4]), o1.x);
    o1.y = fmaf(a, bf2f(v[5]), o1.y);
    o1.z = fmaf(a, bf2f(v[6]), o1.z);
    o1.w = fmaf(a, bf2f(v[7]), o1.w);
}

__global__ __launch_bounds__(256) void sortagg_k(
    const unsigned* __restrict__ ebuf, const int* __restrict__ cursor,
    SortAggArgs A)
{
    const int b = blockIdx.x, ty = blockIdx.y, t = threadIdx.x;
    const int relA = ty;              // 0=dd, 1=tt
    const int relB = ty ? 2 : 3;      // dt : td
    const int nb = A.nb;
    int cntA = cursor[(size_t)relA * MAXNB + b] - b * CAP_B;
    cntA = (cntA < 0) ? 0 : (cntA > CAP_B) ? CAP_B : cntA;
    int cntB = cursor[(size_t)relB * MAXNB + b] - b * CAP_B;
    cntB = (cntB < 0) ? 0 : (cntB > CAP_B) ? CAP_B : cntB;

    __shared__ unsigned list[2 * CAP_B];    // 16 KB: alpha-sorted edges
    __shared__ int histA[128], histB[128], cnt2A[128], cnt2B[128];
    __shared__ int offA[128], offB[128];    // inclusive scans of padded counts
    __shared__ float ssumA[128], ssumB[128];
    __shared__ int totalA_s;

    const unsigned* ebA = ebuf + ((size_t)relA * nb + b) * CAP_B;
    const unsigned* ebB = ebuf + ((size_t)relB * nb + b) * CAP_B;

    if (t < 128) { histA[t] = 0; histB[t] = 0; cnt2A[t] = 0; cnt2B[t] = 0;
                   ssumA[t] = 0.f; ssumB[t] = 0.f; }
    __syncthreads();
    for (int i = t; i < cntA; i += 256) atomicAdd(&histA[ebA[i] >> 16], 1);
    for (int i = t; i < cntB; i += 256) atomicAdd(&histB[ebB[i] >> 16], 1);
    __syncthreads();
    if (t < 128) {
        offA[t] = (histA[t] + 3) & ~3;
        offB[t] = (histB[t] + 3) & ~3;
    }
    __syncthreads();
    for (int o = 1; o < 128; o <<= 1) {
        int vA = 0, vB = 0;
        if (t < 128 && t >= o) { vA = offA[t - o]; vB = offB[t - o]; }
        __syncthreads();
        if (t < 128) { offA[t] += vA; offB[t] += vB; }
        __syncthreads();
    }
    if (t == 127) totalA_s = offA[127];
    __syncthreads();
    const int totalA = totalA_s;
    if (t < 128) {
        const int pcA = (histA[t] + 3) & ~3;
        const int exA = offA[t] - pcA;
        for (int i = exA + histA[t]; i < exA + pcA; ++i) list[i] = 0u;
        const int pcB = (histB[t] + 3) & ~3;
        const int exB = totalA + offB[t] - pcB;
        for (int i = exB + histB[t]; i < exB + pcB; ++i) list[i] = 0u;
    }
    __syncthreads();

    const float* elA = A.elA[ty]; const float* erA = A.erA[ty];
    const float* elB = A.elB[ty]; const float* erB = A.erB[ty];
    for (int i = t; i < cntA; i += 256) {
        const unsigned v = ebA[i];
        const int local = v >> 16;
        const int s = v & 0xffffu;
        const float ex = lrexp(elA[s] + erA[b * 128 + local]);
        atomicAdd(&ssumA[local], ex);
        const int pcA = (histA[local] + 3) & ~3;
        const int p = (offA[local] - pcA) + atomicAdd(&cnt2A[local], 1);
        list[p] = (unsigned)s | ((unsigned)f2h(ex) << 16);
    }
    for (int i = t; i < cntB; i += 256) {
        const unsigned v = ebB[i];
        const int local = v >> 16;
        const int s = v & 0xffffu;
        const float ex = lrexp(elB[s] + erB[b * 128 + local]);
        atomicAdd(&ssumB[local], ex);
        const int pcB = (histB[local] + 3) & ~3;
        const int p = totalA + (offB[local] - pcB) + atomicAdd(&cnt2B[local], 1);
        list[p] = (unsigned)s | ((unsigned)f2h(ex) << 16);
    }
    __syncthreads();
    if (t < 128) {
        if (histA[t] > 0) {
            const float inv = 1.f / ssumA[t];
            const int pcA = (histA[t] + 3) & ~3;
            const int e0 = offA[t] - pcA, e1 = e0 + histA[t];
            for (int i = e0; i < e1; ++i) {
                const unsigned v = list[i];
                const float a = h2f((unsigned short)(v >> 16)) * inv;
                list[i] = (v & 0xffffu) | ((unsigned)f2h(a) << 16);
            }
        }
        if (histB[t] > 0) {
            const float inv = 1.f / ssumB[t];
            const int pcB = (histB[t] + 3) & ~3;
            const int e0 = totalA + offB[t] - pcB, e1 = e0 + histB[t];
            for (int i = e0; i < e1; ++i) {
                const unsigned v = list[i];
                const float a = h2f((unsigned short)(v >> 16)) * inv;
                list[i] = (v & 0xffffu) | ((unsigned)f2h(a) << 16);
            }
        }
    }
    __syncthreads();

    // ---- phase 2: aggregate 128 dsts with 16 groups of 16 lanes ----
    const int lane = t & 15;
    const int grp = t >> 4;
    const unsigned short* fbA = A.fbA[ty];
    const unsigned short* fbB = A.fbB[ty];
    for (int local = grp; local < 128; local += 16) {
        const int d = b * 128 + local;
        if (d >= A.n) continue;
        float4 o0 = ((const float4*)A.pb[ty])[lane * 2];
        float4 o1 = ((const float4*)A.pb[ty])[lane * 2 + 1];

        const int pcA = (histA[local] + 3) & ~3;
        const int exA = offA[local] - pcA;
        for (int k = 0; k < pcA; k += 4) {
            unsigned pv[4];
#pragma unroll
            for (int j = 0; j < 4; ++j) pv[j] = list[exA + k + j];
            u16x8 v[4];
#pragma unroll
            for (int j = 0; j < 4; ++j)
                v[j] = ((const u16x8*)(fbA + (size_t)(pv[j] & 0xffffu) * DD))[lane];
#pragma unroll
            for (int j = 0; j < 4; ++j)
                fma8v(h2f((unsigned short)(pv[j] >> 16)), v[j], o0, o1);
        }
        const int pcB = (histB[local] + 3) & ~3;
        const int exB = totalA + offB[local] - pcB;
        for (int k = 0; k < pcB; k += 4) {
            unsigned pv[4];
#pragma unroll
            for (int j = 0; j < 4; ++j) pv[j] = list[exB + k + j];
            u16x8 v[4];
#pragma unroll
            for (int j = 0; j < 4; ++j)
                v[j] = ((const u16x8*)(fbB + (size_t)(pv[j] & 0xffffu) * DD))[lane];
#pragma unroll
            for (int j = 0; j < 4; ++j)
                fma8v(h2f((unsigned short)(pv[j] >> 16)), v[j], o0, o1);
        }

        // unpermute: stored c' = lane*8 + jj  <->  orig col = jj*16 + lane
        float* op = A.out[ty] + (size_t)d * DD + lane;
        op[0]   = o0.x; op[16]  = o0.y; op[32]  = o0.z; op[48]  = o0.w;
        op[64]  = o1.x; op[80]  = o1.y; op[96]  = o1.z; op[112] = o1.w;
    }
}

// ---------------------------------------------------------------------------
extern "C" void kernel_launch(void* const* d_in, const int* in_sizes, int n_in,
                              void* d_out, int out_size, void* d_ws, size_t ws_size,
                              hipStream_t stream)
{
    const float* x_d  = (const float*)d_in[0];
    const float* x_t  = (const float*)d_in[1];
    const float* W_dd = (const float*)d_in[2];
    const float* W_tt = (const float*)d_in[3];
    const float* W_dt = (const float*)d_in[4];
    const float* al_dd = (const float*)d_in[5];
    const float* ar_dd = (const float*)d_in[6];
    const float* al_tt = (const float*)d_in[7];
    const float* ar_tt = (const float*)d_in[8];
    const float* al_dt = (const float*)d_in[9];
    const float* ar_dt = (const float*)d_in[10];
    const float* b_dd  = (const float*)d_in[11];
    const float* b_tt  = (const float*)d_in[12];
    const float* b_dt  = (const float*)d_in[13];
    const int* src_dd = (const int*)d_in[14];
    const int* dst_dd = (const int*)d_in[15];
    const int* src_tt = (const int*)d_in[16];
    const int* dst_tt = (const int*)d_in[17];
    const int* src_dt = (const int*)d_in[18];
    const int* dst_dt = (const int*)d_in[19];
    const int* src_td = (const int*)d_in[20];
    const int* dst_td = (const int*)d_in[21];

    const int n  = in_sizes[0] / DD;    // 50000
    const int nE = in_sizes[14];        // 500000
    const int nb = (n + 127) >> BSHIFT; // 391

    float* ws = (float*)d_ws;
    size_t off = 0;
    unsigned short* fb_dd   = (unsigned short*)(ws + off); off += (size_t)n * DD / 2;
    unsigned short* fb_tt   = (unsigned short*)(ws + off); off += (size_t)n * DD / 2;
    unsigned short* fb_dt_d = (unsigned short*)(ws + off); off += (size_t)n * DD / 2;
    unsigned short* fb_dt_t = (unsigned short*)(ws + off); off += (size_t)n * DD / 2;
    unsigned* ebuf = (unsigned*)(ws + off); off += (size_t)4 * nb * CAP_B;
    float* el_dd   = ws + off; off += n;
    float* er_dd   = ws + off; off += n;
    float* el_tt   = ws + off; off += n;
    float* er_tt   = ws + off; off += n;
    float* el_dt_d = ws + off; off += n;
    float* er_dt_d = ws + off; off += n;
    float* el_dt_t = ws + off; off += n;
    float* er_dt_t = ws + off; off += n;
    int* cursor = (int*)(ws + off); off += (size_t)4 * MAXNB;
    unsigned short* Wp_dd = (unsigned short*)(ws + off); off += 2048 * 8 / 2;
    unsigned short* Wp_tt = (unsigned short*)(ws + off); off += 2048 * 8 / 2;
    unsigned short* Wp_dt = (unsigned short*)(ws + off); off += 2048 * 8 / 2;
    float* pb0 = ws + off; off += DD;
    float* pb1 = ws + off; off += DD;

    if (ws_size < off * sizeof(float)) return;  // scratch too small -> fail loud

    pack_init_k<<<32, 256, 0, stream>>>(W_dd, W_tt, W_dt, Wp_dd, Wp_tt, Wp_dt,
                                        cursor, b_dd, b_tt, b_dt, pb0, pb1);

    Prep5Args P;
    P.x[0] = x_d; P.x[1] = x_t; P.x[2] = x_d; P.x[3] = x_t;
    P.Wp[0] = Wp_dd; P.Wp[1] = Wp_tt; P.Wp[2] = Wp_dt; P.Wp[3] = Wp_dt;
    P.al[0] = al_dd; P.al[1] = al_tt; P.al[2] = al_dt; P.al[3] = al_dt;
    P.ar[0] = ar_dd; P.ar[1] = ar_tt; P.ar[2] = ar_dt; P.ar[3] = ar_dt;
    P.fb[0] = fb_dd; P.fb[1] = fb_tt; P.fb[2] = fb_dt_d; P.fb[3] = fb_dt_t;
    P.el[0] = el_dd; P.el[1] = el_tt; P.el[2] = el_dt_d; P.el[3] = el_dt_t;
    P.er[0] = er_dd; P.er[1] = er_tt; P.er[2] = er_dt_d; P.er[3] = er_dt_t;
    P.src[0] = src_dd; P.dst[0] = dst_dd;
    P.src[1] = src_tt; P.dst[1] = dst_tt;
    P.src[2] = src_dt; P.dst[2] = dst_dt;
    P.src[3] = src_td; P.dst[3] = dst_td;
    P.cursor = cursor; P.ebuf = ebuf;
    P.n = n; P.nE = nE; P.nb = nb;

    int gx = (n + 127) / 128;                // 391
    if (gx < 4 * NSCAT) gx = 4 * NSCAT;      // 640
    dim3 pgrid(gx, 5);
    prep5_k<<<pgrid, 512, 0, stream>>>(P);

    SortAggArgs A;
    A.elA[0] = el_dd;   A.erA[0] = er_dd;    // ty=0: rel dd
    A.elA[1] = el_tt;   A.erA[1] = er_tt;    // ty=1: rel tt
    A.elB[0] = el_dt_t; A.erB[0] = er_dt_d;  // ty=0: rel td (src=t, dst=d)
    A.elB[1] = el_dt_d; A.erB[1] = er_dt_t;  // ty=1: rel dt (src=d, dst=t)
    A.fbA[0] = fb_dd;   A.fbA[1] = fb_tt;
    A.fbB[0] = fb_dt_t; A.fbB[1] = fb_dt_d;
    A.pb[0] = pb0; A.pb[1] = pb1;
    A.out[0] = (float*)d_out;
    A.out[1] = (float*)d_out + (size_t)n * DD;
    A.n = n; A.nb = nb;

    dim3 agrid(nb, 2);
    sortagg_k<<<agrid, 256, 0, stream>>>(ebuf, cursor, A);
}

// Round 18
// 144.576 us; speedup vs baseline: 1.0540x; 1.0540x over previous
//
#include <hip/hip_runtime.h>
#include <hip/hip_bf16.h>
#include <hip/hip_fp16.h>
#include <math.h>

#define DD 128
#define NEG_SLOPE 0.2f
#define CAP_B 2048          // per-bucket capacity (mean 1280 + pad)
#define BSHIFT 7            // bucket = dst >> 7 (128 dsts/bucket)
#define MAXNB 512
#define NSCAT 160           // scatter blocks per relation

typedef __attribute__((ext_vector_type(8))) short bf16x8;
typedef __attribute__((ext_vector_type(4))) float f32x4;
typedef __attribute__((ext_vector_type(8))) unsigned short u16x8;

__device__ __forceinline__ short f2bf(float f) {
    __hip_bfloat16 h = __float2bfloat16(f);
    return __builtin_bit_cast(short, h);
}
__device__ __forceinline__ float bf2f(unsigned short u) {
    return __uint_as_float(((unsigned)u) << 16);
}
__device__ __forceinline__ unsigned short f2h(float f) {
    return __builtin_bit_cast(unsigned short, __float2half(f));
}
__device__ __forceinline__ float h2f(unsigned short u) {
    return __half2float(__builtin_bit_cast(__half, u));
}
__device__ __forceinline__ float lrexp(float e) {
    e = (e > 0.f) ? e : NEG_SLOPE * e;
    return __expf(e);
}

// fb column permutation: stored col c' <-> original col (c'&7)*16 + (c'>>3)
__device__ __forceinline__ int permcol(int cp) { return (cp & 7) * 16 + (cp >> 3); }

// ---------------------------------------------------------------------------
// Pack 3 W matrices into bf16 MFMA-B fragment order + init cursors + permuted
// bias sums (pb0 = b_dd+b_dt, pb1 = b_tt+b_dt, both in fb column order).
__global__ __launch_bounds__(256) void pack_init_k(
    const float* __restrict__ W0, const float* __restrict__ W1,
    const float* __restrict__ W2,
    unsigned short* __restrict__ P0, unsigned short* __restrict__ P1,
    unsigned short* __restrict__ P2, int* __restrict__ cursor,
    const float* __restrict__ b_dd, const float* __restrict__ b_tt,
    const float* __restrict__ b_dt, float* __restrict__ pb0,
    float* __restrict__ pb1)
{
    if (blockIdx.x >= 24) {
        const int i = (blockIdx.x - 24) * 256 + threadIdx.x;
        if (i < 4 * MAXNB) cursor[i] = (i & (MAXNB - 1)) * CAP_B;
        if (blockIdx.x == 24) {
            const int t = threadIdx.x;
            if (t < 128) pb0[t] = b_dd[permcol(t)] + b_dt[permcol(t)];
            else         pb1[t - 128] = b_tt[permcol(t - 128)] + b_dt[permcol(t - 128)];
        }
        return;
    }
    const int t = blockIdx.x * 256 + threadIdx.x;
    const int m = t >> 11;
    const int r = t & 2047;
    const float* W = (m == 0) ? W0 : (m == 1) ? W1 : W2;
    unsigned short* P = (m == 0) ? P0 : (m == 1) ? P1 : P2;
    const int lane = r & 63;
    const int tile = r >> 6;
    const int ks = tile >> 3, ct = tile & 7;
    const int col = ct * 16 + (lane & 15);
    const int k0 = ks * 32 + (lane >> 4) * 8;
#pragma unroll
    for (int j = 0; j < 8; ++j)
        P[(size_t)r * 8 + j] = (unsigned short)f2bf(W[(size_t)(k0 + j) * DD + col]);
}

// ---------------------------------------------------------------------------
// Epilogue with permuted vectorized store (fb column order = c').
__device__ __forceinline__ void epi_store(
    f32x4 acc[8], const float* __restrict__ al, const float* __restrict__ ar,
    unsigned short* __restrict__ fb, float* __restrict__ el,
    float* __restrict__ er, int r0, int lane, int nrows)
{
    float pl[4] = {0.f, 0.f, 0.f, 0.f};
    float pr[4] = {0.f, 0.f, 0.f, 0.f};
#pragma unroll
    for (int ct = 0; ct < 8; ++ct) {
        const float alc = al[ct * 16 + (lane & 15)];
        const float arc = ar[ct * 16 + (lane & 15)];
#pragma unroll
        for (int g = 0; g < 4; ++g) {
            pl[g] = fmaf(acc[ct][g], alc, pl[g]);
            pr[g] = fmaf(acc[ct][g], arc, pr[g]);
        }
    }
#pragma unroll
    for (int o = 1; o < 16; o <<= 1) {
#pragma unroll
        for (int g = 0; g < 4; ++g) {
            pl[g] += __shfl_xor(pl[g], o, 16);
            pr[g] += __shfl_xor(pr[g], o, 16);
        }
    }
    if ((lane & 15) == 0) {
#pragma unroll
        for (int g = 0; g < 4; ++g) {
            const int r = r0 + (lane >> 4) * 4 + g;
            if (r < nrows) { el[r] = pl[g]; er[r] = pr[g]; }
        }
    }
#pragma unroll
    for (int g = 0; g < 4; ++g) {
        const int r = r0 + (lane >> 4) * 4 + g;
        if (r < nrows) {
            u16x8 v;
#pragma unroll
            for (int ct = 0; ct < 8; ++ct)
                v[ct] = (unsigned short)f2bf(acc[ct][g]);
            *((u16x8*)(fb + (size_t)r * DD + (lane & 15) * 8)) = v;
        }
    }
}

// ---------------------------------------------------------------------------
// Heterogeneous prep: grid.y = 0..3 -> transform variant v (W in 32KB LDS,
// 8 waves x 16 rows); grid.y = 4 -> bucket scatter (NSCAT blocks/relation).
struct Prep5Args {
    const float* x[4];
    const unsigned short* Wp[4];
    const float* al[4]; const float* ar[4];
    unsigned short* fb[4]; float* el[4]; float* er[4];
    const int* src[4]; const int* dst[4];
    int* cursor; unsigned* ebuf;
    int n, nE, nb;
};

__global__ __launch_bounds__(512) void prep5_k(Prep5Args P)
{
    __shared__ unsigned short wlds[2048 * 8];   // 32 KB

    const int v = blockIdx.y;
    if (v < 4) {
        const int lane = threadIdx.x & 63;
        const int wave = threadIdx.x >> 6;          // 0..7
        const int r0 = (blockIdx.x * 8 + wave) * 16;
        if (blockIdx.x * 128 >= P.n) return;

        const uint4* wsrc = (const uint4*)P.Wp[v];
        uint4* wdst = (uint4*)wlds;
#pragma unroll
        for (int i = 0; i < 4; ++i)
            wdst[threadIdx.x + i * 512] = wsrc[threadIdx.x + i * 512];
        __syncthreads();

        if (r0 >= P.n) return;
        const int arow = r0 + (lane & 15);
        const int arow_c = (arow < P.n) ? arow : (P.n - 1);
        const int kbase = (lane >> 4) * 8;
        const float* x = P.x[v];

        f32x4 acc[8];
#pragma unroll
        for (int ct = 0; ct < 8; ++ct) acc[ct] = (f32x4)(0.f);

#pragma unroll
        for (int ks = 0; ks < 4; ++ks) {
            const float* xp = x + (size_t)arow_c * DD + ks * 32 + kbase;
            const float4 a0 = ((const float4*)xp)[0];
            const float4 a1 = ((const float4*)xp)[1];
            bf16x8 af;
            af[0] = f2bf(a0.x); af[1] = f2bf(a0.y); af[2] = f2bf(a0.z); af[3] = f2bf(a0.w);
            af[4] = f2bf(a1.x); af[5] = f2bf(a1.y); af[6] = f2bf(a1.z); af[7] = f2bf(a1.w);
#pragma unroll
            for (int ct = 0; ct < 8; ++ct) {
                const bf16x8 w = *((const bf16x8*)(wlds + ((size_t)(ks * 8 + ct) * 64 + lane) * 8));
                acc[ct] = __builtin_amdgcn_mfma_f32_16x16x32_bf16(af, w, acc[ct], 0, 0, 0);
            }
        }
        epi_store(acc, P.al[v], P.ar[v], P.fb[v], P.el[v], P.er[v], r0, lane, P.n);
        return;
    }

    // ---- bucket scatter (512 threads; aliases wlds for counters) ----
    const int sb = blockIdx.x;
    if (sb >= 4 * NSCAT) return;
    int* cnt_s  = (int*)wlds;
    int* base_s = ((int*)wlds) + MAXNB;
    const int rel = sb / NSCAT;
    const int blk = sb - rel * NSCAT;
    const int* src = P.src[rel];
    const int* dst = P.dst[rel];
    int* cur = P.cursor + (size_t)rel * MAXNB;
    unsigned* eb = P.ebuf + (size_t)rel * P.nb * CAP_B;

    const int t = threadIdx.x;
    const int ch = (P.nE + NSCAT - 1) / NSCAT;
    const int i0 = blk * ch;
    const int i1 = (i0 + ch < P.nE) ? (i0 + ch) : P.nE;

    for (int i = t; i < MAXNB; i += 512) cnt_s[i] = 0;
    __syncthreads();
    for (int i = i0 + t; i < i1; i += 512)
        atomicAdd(&cnt_s[dst[i] >> BSHIFT], 1);
    __syncthreads();
    for (int b = t; b < P.nb; b += 512) {
        const int c = cnt_s[b];
        base_s[b] = c ? atomicAdd(cur + b, c) : 0;
        cnt_s[b] = 0;
    }
    __syncthreads();
    for (int i = i0 + t; i < i1; i += 512) {
        const int dv = dst[i];
        const int b = dv >> BSHIFT;
        const int p = base_s[b] + atomicAdd(&cnt_s[b], 1);
        eb[p] = ((unsigned)(dv & ((1 << BSHIFT) - 1)) << 16) | (unsigned)src[i];
    }
}

// ---------------------------------------------------------------------------
// Per-bucket LDS counting sort + softmax finalize (alpha precomputed, padded).
struct SortArgs {
    const float* el[4]; const float* er[4];
};

__global__ __launch_bounds__(256) void sort_alpha_k(
    const unsigned* __restrict__ ebuf, const int* __restrict__ cursor,
    SortArgs S, unsigned* __restrict__ cs32, int* __restrict__ rstart,
    int* __restrict__ rdeg, int n, int nb)
{
    const int b = blockIdx.x, rel = blockIdx.y, t = threadIdx.x;
    int cnt = cursor[(size_t)rel * MAXNB + b] - b * CAP_B;
    cnt = (cnt < 0) ? 0 : (cnt > CAP_B) ? CAP_B : cnt;

    __shared__ unsigned buf[CAP_B];
    __shared__ unsigned out32[CAP_B];
    __shared__ int hist[128], off[128], cnt2[128], excl[128];
    __shared__ float ssum[128];
    __shared__ int total_s;

    const unsigned* ebr = ebuf + ((size_t)rel * nb + b) * CAP_B;
    for (int i = t; i < cnt; i += 256) buf[i] = ebr[i];
    if (t < 128) { hist[t] = 0; cnt2[t] = 0; ssum[t] = 0.f; }
    __syncthreads();
    for (int i = t; i < cnt; i += 256) atomicAdd(&hist[buf[i] >> 16], 1);
    __syncthreads();
    if (t < 128) off[t] = (hist[t] + 3) & ~3;
    __syncthreads();
    for (int o = 1; o < 128; o <<= 1) {
        const int v = (t < 128 && t >= o) ? off[t - o] : 0;
        __syncthreads();
        if (t < 128) off[t] += v;
        __syncthreads();
    }
    if (t < 128) {
        const int pc = (hist[t] + 3) & ~3;
        excl[t] = off[t] - pc;
        const int d = b * 128 + t;
        if (d < n) {
            rstart[(size_t)rel * n + d] = b * CAP_B + excl[t];
            rdeg[(size_t)rel * n + d] = pc;
        }
        for (int i = excl[t] + hist[t]; i < off[t]; ++i) out32[i] = 0u;
    }
    if (t == 127) total_s = off[127];
    __syncthreads();

    const float* el = S.el[rel];
    const float* er = S.er[rel];
    for (int i = t; i < cnt; i += 256) {
        const unsigned v = buf[i];
        const int local = v >> 16;
        const int s = v & 0xffffu;
        const float ex = lrexp(el[s] + er[b * 128 + local]);
        atomicAdd(&ssum[local], ex);
        const int p = excl[local] + atomicAdd(&cnt2[local], 1);
        out32[p] = (unsigned)s | ((unsigned)f2h(ex) << 16);
    }
    __syncthreads();
    if (t < 128 && hist[t] > 0) {
        const float inv = 1.f / ssum[t];
        const int e0 = excl[t], e1 = excl[t] + hist[t];
        for (int i = e0; i < e1; ++i) {
            const unsigned v = out32[i];
            const float alpha = h2f((unsigned short)(v >> 16)) * inv;
            out32[i] = (v & 0xffffu) | ((unsigned)f2h(alpha) << 16);
        }
    }
    __syncthreads();
    unsigned* cs = cs32 + ((size_t)rel * nb + b) * CAP_B;
    const int total = total_s;
    for (int i = t; i < total; i += 256) cs[i] = out32[i];
}

// ---------------------------------------------------------------------------
// Lean fused aggregation with unroll-8 MLP: out = pbias + sum(alpha*fb_row).
struct AggArgs {
    const int* rs[4]; const int* rd[4];
    const unsigned* cs[4];
    const unsigned short* fb[4];
    const float* pb[2];
    float* out[2];
    int n;
};

__device__ __forceinline__ void fma8(
    float a, const u16x8& v, float4& o0, float4& o1)
{
    o0.x = fmaf(a, bf2f(v[0]), o0.x);
    o0.y = fmaf(a, bf2f(v[1]), o0.y);
    o0.z = fmaf(a, bf2f(v[2]), o0.z);
    o0.w = fmaf(a, bf2f(v[3]), o0.w);
    o1.x = fmaf(a, bf2f(v[4]), o1.x);
    o1.y = fmaf(a, bf2f(v[5]), o1.y);
    o1.z = fmaf(a, bf2f(v[6]), o1.z);
    o1.w = fmaf(a, bf2f(v[7]), o1.w);
}

__device__ __forceinline__ void agg16p(
    const int* __restrict__ rs, const int* __restrict__ rd,
    const unsigned* __restrict__ cs, const unsigned short* __restrict__ fb,
    int d, int lane, float4& o0, float4& o1)
{
    const int cnt = rd[d];
    if (cnt == 0) return;
    const unsigned* csp = cs + rs[d];
    int k = 0;
    for (; k + 8 <= cnt; k += 8) {
        unsigned pv[8];
#pragma unroll
        for (int j = 0; j < 8; ++j) pv[j] = csp[k + j];
        u16x8 v[8];
#pragma unroll
        for (int j = 0; j < 8; ++j)
            v[j] = ((const u16x8*)(fb + (size_t)(pv[j] & 0xffffu) * DD))[lane];
#pragma unroll
        for (int j = 0; j < 8; ++j)
            fma8(h2f((unsigned short)(pv[j] >> 16)), v[j], o0, o1);
    }
    for (; k + 4 <= cnt; k += 4) {
        unsigned pv[4];
#pragma unroll
        for (int j = 0; j < 4; ++j) pv[j] = csp[k + j];
        u16x8 v[4];
#pragma unroll
        for (int j = 0; j < 4; ++j)
            v[j] = ((const u16x8*)(fb + (size_t)(pv[j] & 0xffffu) * DD))[lane];
#pragma unroll
        for (int j = 0; j < 4; ++j)
            fma8(h2f((unsigned short)(pv[j] >> 16)), v[j], o0, o1);
    }
}

__global__ __launch_bounds__(256) void gat_aggregate_f(AggArgs A)
{
    const int lane = threadIdx.x & 15;
    const int grp  = threadIdx.x >> 4;
    const int gid = blockIdx.x * 16 + grp;
    if (gid >= 2 * A.n) return;
    const int ty = (gid >= A.n) ? 1 : 0;
    const int d = gid - ty * A.n;
    const int sl1 = ty ? 1 : 0;
    const int sl2 = ty ? 2 : 3;

    float4 o0 = ((const float4*)A.pb[ty])[lane * 2];
    float4 o1 = ((const float4*)A.pb[ty])[lane * 2 + 1];

    agg16p(A.rs[sl1], A.rd[sl1], A.cs[sl1], A.fb[sl1], d, lane, o0, o1);
    agg16p(A.rs[sl2], A.rd[sl2], A.cs[sl2], A.fb[sl2], d, lane, o0, o1);

    // unpermute: stored c' = lane*8 + jj  <->  orig col = jj*16 + lane
    float* op = A.out[ty] + (size_t)d * DD + lane;
    op[0]   = o0.x; op[16]  = o0.y; op[32]  = o0.z; op[48]  = o0.w;
    op[64]  = o1.x; op[80]  = o1.y; op[96]  = o1.z; op[112] = o1.w;
}

// ---------------------------------------------------------------------------
extern "C" void kernel_launch(void* const* d_in, const int* in_sizes, int n_in,
                              void* d_out, int out_size, void* d_ws, size_t ws_size,
                              hipStream_t stream)
{
    const float* x_d  = (const float*)d_in[0];
    const float* x_t  = (const float*)d_in[1];
    const float* W_dd = (const float*)d_in[2];
    const float* W_tt = (const float*)d_in[3];
    const float* W_dt = (const float*)d_in[4];
    const float* al_dd = (const float*)d_in[5];
    const float* ar_dd = (const float*)d_in[6];
    const float* al_tt = (const float*)d_in[7];
    const float* ar_tt = (const float*)d_in[8];
    const float* al_dt = (const float*)d_in[9];
    const float* ar_dt = (const float*)d_in[10];
    const float* b_dd  = (const float*)d_in[11];
    const float* b_tt  = (const float*)d_in[12];
    const float* b_dt  = (const float*)d_in[13];
    const int* src_dd = (const int*)d_in[14];
    const int* dst_dd = (const int*)d_in[15];
    const int* src_tt = (const int*)d_in[16];
    const int* dst_tt = (const int*)d_in[17];
    const int* src_dt = (const int*)d_in[18];
    const int* dst_dt = (const int*)d_in[19];
    const int* src_td = (const int*)d_in[20];
    const int* dst_td = (const int*)d_in[21];

    const int n  = in_sizes[0] / DD;    // 50000
    const int nE = in_sizes[14];        // 500000
    const int nb = (n + 127) >> BSHIFT; // 391

    float* ws = (float*)d_ws;
    size_t off = 0;
    unsigned short* fb_dd   = (unsigned short*)(ws + off); off += (size_t)n * DD / 2;
    unsigned short* fb_tt   = (unsigned short*)(ws + off); off += (size_t)n * DD / 2;
    unsigned short* fb_dt_d = (unsigned short*)(ws + off); off += (size_t)n * DD / 2;
    unsigned short* fb_dt_t = (unsigned short*)(ws + off); off += (size_t)n * DD / 2;
    unsigned* ebuf = (unsigned*)(ws + off); off += (size_t)4 * nb * CAP_B;
    unsigned* cs32 = (unsigned*)(ws + off); off += (size_t)4 * nb * CAP_B;
    float* el_dd   = ws + off; off += n;
    float* er_dd   = ws + off; off += n;
    float* el_tt   = ws + off; off += n;
    float* er_tt   = ws + off; off += n;
    float* el_dt_d = ws + off; off += n;
    float* er_dt_d = ws + off; off += n;
    float* el_dt_t = ws + off; off += n;
    float* er_dt_t = ws + off; off += n;
    int* rstart = (int*)(ws + off); off += (size_t)4 * n;
    int* rdeg   = (int*)(ws + off); off += (size_t)4 * n;
    int* cursor = (int*)(ws + off); off += (size_t)4 * MAXNB;
    unsigned short* Wp_dd = (unsigned short*)(ws + off); off += 2048 * 8 / 2;
    unsigned short* Wp_tt = (unsigned short*)(ws + off); off += 2048 * 8 / 2;
    unsigned short* Wp_dt = (unsigned short*)(ws + off); off += 2048 * 8 / 2;
    float* pb0 = ws + off; off += DD;
    float* pb1 = ws + off; off += DD;

    if (ws_size < off * sizeof(float)) return;  // scratch too small -> fail loud

    pack_init_k<<<32, 256, 0, stream>>>(W_dd, W_tt, W_dt, Wp_dd, Wp_tt, Wp_dt,
                                        cursor, b_dd, b_tt, b_dt, pb0, pb1);

    Prep5Args P;
    P.x[0] = x_d; P.x[1] = x_t; P.x[2] = x_d; P.x[3] = x_t;
    P.Wp[0] = Wp_dd; P.Wp[1] = Wp_tt; P.Wp[2] = Wp_dt; P.Wp[3] = Wp_dt;
    P.al[0] = al_dd; P.al[1] = al_tt; P.al[2] = al_dt; P.al[3] = al_dt;
    P.ar[0] = ar_dd; P.ar[1] = ar_tt; P.ar[2] = ar_dt; P.ar[3] = ar_dt;
    P.fb[0] = fb_dd; P.fb[1] = fb_tt; P.fb[2] = fb_dt_d; P.fb[3] = fb_dt_t;
    P.el[0] = el_dd; P.el[1] = el_tt; P.el[2] = el_dt_d; P.el[3] = el_dt_t;
    P.er[0] = er_dd; P.er[1] = er_tt; P.er[2] = er_dt_d; P.er[3] = er_dt_t;
    P.src[0] = src_dd; P.dst[0] = dst_dd;
    P.src[1] = src_tt; P.dst[1] = dst_tt;
    P.src[2] = src_dt; P.dst[2] = dst_dt;
    P.src[3] = src_td; P.dst[3] = dst_td;
    P.cursor = cursor; P.ebuf = ebuf;
    P.n = n; P.nE = nE; P.nb = nb;

    int gx = (n + 127) / 128;                // 8 waves x 16 rows = 128 rows/block
    if (gx < 4 * NSCAT) gx = 4 * NSCAT;      // 640
    dim3 pgrid(gx, 5);
    prep5_k<<<pgrid, 512, 0, stream>>>(P);

    SortArgs S;
    // rel slots: 0=dd, 1=tt, 2=dt(dst=t), 3=td(dst=d)
    S.el[0] = el_dd;   S.er[0] = er_dd;
    S.el[1] = el_tt;   S.er[1] = er_tt;
    S.el[2] = el_dt_d; S.er[2] = er_dt_t;
    S.el[3] = el_dt_t; S.er[3] = er_dt_d;
    dim3 bgrid(nb, 4);
    sort_alpha_k<<<bgrid, 256, 0, stream>>>(ebuf, cursor, S, cs32, rstart, rdeg, n, nb);

    const size_t reg = (size_t)nb * CAP_B;
    AggArgs A;
    A.rs[0] = rstart + 0 * (size_t)n; A.rd[0] = rdeg + 0 * (size_t)n;
    A.rs[1] = rstart + 1 * (size_t)n; A.rd[1] = rdeg + 1 * (size_t)n;
    A.rs[2] = rstart + 2 * (size_t)n; A.rd[2] = rdeg + 2 * (size_t)n;
    A.rs[3] = rstart + 3 * (size_t)n; A.rd[3] = rdeg + 3 * (size_t)n;
    A.cs[0] = cs32 + 0 * reg; A.cs[1] = cs32 + 1 * reg;
    A.cs[2] = cs32 + 2 * reg; A.cs[3] = cs32 + 3 * reg;
    A.fb[0] = fb_dd; A.fb[1] = fb_tt;
    A.fb[2] = fb_dt_d;   // dt: src type d
    A.fb[3] = fb_dt_t;   // td: src type t
    A.pb[0] = pb0; A.pb[1] = pb1;
    A.out[0] = (float*)d_out;
    A.out[1] = (float*)d_out + (size_t)n * DD;
    A.n = n;

    const int aggrid = (2 * n + 15) / 16;
    gat_aggregate_f<<<aggrid, 256, 0, stream>>>(A);
}